// Round 16
// baseline (176.566 us; speedup 1.0000x reference)
//
#include <hip/hip_runtime.h>
#include <stdint.h>

#define H_    16
#define HKV_  4
#define D_    128
#define S_    2048
#define HID_  2048
#define RLEN_ 2048

typedef unsigned short u16;
typedef __attribute__((ext_vector_type(4))) float f32x4;
typedef __attribute__((ext_vector_type(16))) float f32x16;
typedef __attribute__((ext_vector_type(8))) __bf16 bf16x8;
typedef __attribute__((ext_vector_type(4))) unsigned short u16x4;
typedef __attribute__((ext_vector_type(8))) unsigned short u16x8;
typedef __attribute__((ext_vector_type(2))) unsigned int u32x2;

__device__ __forceinline__ u16 f2bf(float f) {
  union { float f; unsigned u; } v; v.f = f;
  unsigned r = v.u + 0x7FFFu + ((v.u >> 16) & 1u);
  return (u16)(r >> 16);
}
__device__ __forceinline__ float bf2f(u16 h) {
  union { unsigned u; float f; } v; v.u = ((unsigned)h) << 16;
  return v.f;
}
__device__ __forceinline__ float exp2v(float x) {  // exact v_exp_f32 (2^x)
  float r; asm("v_exp_f32 %0, %1" : "=v"(r) : "v"(x)); return r;
}
__device__ __forceinline__ unsigned cvtpk(float lo, float hi) {
  unsigned r; asm("v_cvt_pk_bf16_f32 %0, %1, %2" : "=v"(r) : "v"(lo), "v"(hi)); return r;
}
__device__ __forceinline__ void pl32swap(unsigned &a, unsigned &b) {
  u32x2 r = __builtin_amdgcn_permlane32_swap(a, b, false, false);
  a = r.x; b = r.y;  // a' = [a_lo|b_lo], b' = [a_hi|b_hi]
}
__device__ __forceinline__ float xhalf_max(float v) {
  unsigned a = __float_as_uint(v), b = a;
  pl32swap(a, b);
  return fmaxf(__uint_as_float(a), __uint_as_float(b));
}
__device__ __forceinline__ float xhalf_add(float v) {
  unsigned a = __float_as_uint(v), b = a;
  pl32swap(a, b);
  return __uint_as_float(a) + __uint_as_float(b);
}
// Explicit DMA/LDS drain before barriers handing a GLL-target buffer to readers
// (R8 lesson: the compiler's implicit vmcnt(0)-at-barrier is NOT guaranteed).
__device__ __forceinline__ void drain_then_sync() {
  asm volatile("s_waitcnt vmcnt(0) lgkmcnt(0)" ::: "memory");
  __syncthreads();
}
__device__ __forceinline__ void drain4_then_sync() {
  asm volatile("s_waitcnt vmcnt(4) lgkmcnt(0)" ::: "memory");
  __syncthreads();
}
// GEMM pipeline: 6 GLLs/wave/step, 12 outstanding after stage(s+2); <=6 proves L(s+1).
__device__ __forceinline__ void drain6_then_sync() {
  asm volatile("s_waitcnt vmcnt(6) lgkmcnt(0)" ::: "memory");
  __syncthreads();
}

#define GLL(srcp, ldsp) \
  __builtin_amdgcn_global_load_lds((const __attribute__((address_space(1))) unsigned int*)(srcp), \
                                   (__attribute__((address_space(3))) unsigned int*)(ldsp), 16, 0, 0)

// ---------------- fp32 -> bf16 elementwise ----------------
__global__ void k_cvt(const float* __restrict__ in, u16* __restrict__ out, int n4) {
  int i = blockIdx.x * 256 + threadIdx.x;
  if (i >= n4) return;
  float4 v = ((const float4*)in)[i];
  u16x4 o;
  o.x = f2bf(v.x); o.y = f2bf(v.y); o.z = f2bf(v.z); o.w = f2bf(v.w);
  ((u16x4*)out)[i] = o;
}

// ------- fused Wq|Wk|Wv fp32 (K x N) -> bf16 transposed (N x K); one launch -------
__global__ void k_transw_qkv(const float* __restrict__ Wq, const float* __restrict__ Wk,
                             const float* __restrict__ Wv, u16* __restrict__ wtq) {
  __shared__ float tile[32][33];
  const int bid = blockIdx.x;
  const float* in; u16* out; int N, bx, by;
  if (bid < 4096)      { in = Wq; out = wtq;                          N = 2048; bx = (bid & 63) * 32;        by = (bid >> 6) * 32; }
  else if (bid < 5120) { in = Wk; out = wtq + (size_t)2048 * 2048;    N = 512;  bx = ((bid - 4096) & 15) * 32; by = ((bid - 4096) >> 4) * 32; }
  else                 { in = Wv; out = wtq + (size_t)2560 * 2048;    N = 512;  bx = ((bid - 5120) & 15) * 32; by = ((bid - 5120) >> 4) * 32; }
  const int K = 2048;
  int tx = threadIdx.x, ty = threadIdx.y;  // 32 x 8
#pragma unroll
  for (int i = 0; i < 32; i += 8)
    tile[ty + i][tx] = in[(size_t)(by + ty + i) * N + bx + tx];
  __syncthreads();
#pragma unroll
  for (int i = 0; i < 32; i += 8)
    out[(size_t)(bx + ty + i) * K + by + tx] = f2bf(tile[tx][ty + i]);
}

// ---------------- fp32 (K x N) -> bf16 transposed (N x K) ----------------
__global__ void k_transw(const float* __restrict__ in, u16* __restrict__ out, int K, int N) {
  __shared__ float tile[32][33];
  int bx = blockIdx.x * 32, by = blockIdx.y * 32;
  int tx = threadIdx.x, ty = threadIdx.y;  // 32 x 8
#pragma unroll
  for (int i = 0; i < 32; i += 8)
    tile[ty + i][tx] = in[(size_t)(by + ty + i) * N + bx + tx];
  __syncthreads();
#pragma unroll
  for (int i = 0; i < 32; i += 8)
    out[(size_t)(bx + ty + i) * K + by + tx] = f2bf(tile[tx][ty + i]);
}

// ---- bf16 GEMM v3: 256(M)x128(N) block, 4 waves (2Mx2N), wave-tile 128x64 ----
// R16: 2x work per barrier (32 MFMA : 12 ds_read per wave-step), LDS bytes/FLOP x0.75,
// step ~2x longer so the 2-deep counted pipeline covers HBM latency (~1200cy > 900cy).
// 3 buffers x (A 16KB + B 8KB) = 72KB -> 2 blocks/CU. T2 col-slot swizzle retained.
// Grid: (N/128, M/256, Z) split-K.
__global__ __launch_bounds__(256, 2) void k_gemm(const u16* __restrict__ A, const u16* __restrict__ Bt,
                                                 u16* __restrict__ Cb, int M, int N, int K,
                                                 int Kpart, int Krem) {
  __shared__ __attribute__((aligned(16))) u16 As[3][256 * 32];
  __shared__ __attribute__((aligned(16))) u16 Bs[3][128 * 32];
  const int bm = blockIdx.y * 256, bn = blockIdx.x * 128;
  const int kz0 = blockIdx.z * Kpart;
  const int kz1 = kz0 + Kpart + ((blockIdx.z == gridDim.z - 1) ? Krem : 0);
  const int nsteps = (kz1 - kz0) >> 5;
  u16* C = Cb + (size_t)blockIdx.z * M * N;
  const int tid = threadIdx.x, wave = tid >> 6, lane = tid & 63;
  const int wrM = wave >> 1, wcN = wave & 1;
  const int l15 = lane & 15, lhi = lane >> 4;
  const int so = wave * 512;   // u16: per-wave 1KB GLL segment
  f32x4 acc[8][4] = {};
  // T2: per-lane source col-slot = (tid&3) ^ P(row), P(row)=(row>>1)&3, row=tid>>2
  const int cw = ((tid & 3) ^ ((tid >> 3) & 3)) * 8;
  const u16* pA0 = A + (size_t)(bm + (tid >> 2)) * K + cw;          // rows   0..63
  const u16* pA1 = A + (size_t)(bm + 64 + (tid >> 2)) * K + cw;     // rows  64..127
  const u16* pA2 = A + (size_t)(bm + 128 + (tid >> 2)) * K + cw;    // rows 128..191
  const u16* pA3 = A + (size_t)(bm + 192 + (tid >> 2)) * K + cw;    // rows 192..255
  const u16* pB0 = Bt + (size_t)(bn + (tid >> 2)) * K + cw;
  const u16* pB1 = Bt + (size_t)(bn + 64 + (tid >> 2)) * K + cw;
  // T2 fragment-read slot: lhi ^ P(row), row = ..+m*16+l15 -> P=(l15>>1)&3
  const int sc = (lhi ^ ((l15 >> 1) & 3)) * 8;

  auto stage = [&](int s, int buf) {  // 6 GLLs per wave
    const int k0 = kz0 + s * 32;
    GLL(pA0 + k0, &As[buf][so]);
    GLL(pA1 + k0, &As[buf][2048 + so]);
    GLL(pA2 + k0, &As[buf][4096 + so]);
    GLL(pA3 + k0, &As[buf][6144 + so]);
    GLL(pB0 + k0, &Bs[buf][so]);
    GLL(pB1 + k0, &Bs[buf][2048 + so]);
  };

  stage(0, 0);
  if (nsteps > 1) { stage(1, 1); drain6_then_sync(); }
  else            { drain_then_sync(); }

  for (int s = 0; s < nsteps; s++) {
    const int buf = s % 3;
    const bool deep = (s + 2 < nsteps);
    if (deep) stage(s + 2, (s + 2) % 3);
    bf16x8 af[8], bfr[4];
#pragma unroll
    for (int m = 0; m < 8; m++)
      af[m] = *(const bf16x8*)(&As[buf][(wrM * 128 + m * 16 + l15) * 32 + sc]);
#pragma unroll
    for (int n = 0; n < 4; n++)
      bfr[n] = *(const bf16x8*)(&Bs[buf][(wcN * 64 + n * 16 + l15) * 32 + sc]);
#pragma unroll
    for (int m = 0; m < 8; m++)
#pragma unroll
      for (int n = 0; n < 4; n++)
        acc[m][n] = __builtin_amdgcn_mfma_f32_16x16x32_bf16(af[m], bfr[n], acc[m][n], 0, 0, 0);
    if (deep) drain6_then_sync();   // L(s+1) landed; L(s+2) stays in flight
    else      drain_then_sync();    // tail: full drain
  }
  const int r0 = bm + wrM * 128, c0 = bn + wcN * 64;
#pragma unroll
  for (int m = 0; m < 8; m++)
#pragma unroll
    for (int n = 0; n < 4; n++) {
      int r = r0 + m * 16 + lhi * 4, cc = c0 + n * 16 + l15;
#pragma unroll
      for (int j = 0; j < 4; j++)
        C[(size_t)(r + j) * N + cc] = f2bf(acc[m][n][j]);
    }
}

// ---------------- fp32 out = sum of 4 bf16 partials (gemm2) ----------------
__global__ void k_comb4(const u16* __restrict__ c0, float* __restrict__ out, int n8) {
  int i = blockIdx.x * 256 + threadIdx.x;
  if (i >= n8) return;
  const size_t zs = (size_t)2048 * 2048 / 8;  // partial stride in u16x8 units
  u16x8 a = ((const u16x8*)c0)[i];
  u16x8 b = ((const u16x8*)c0)[i + zs];
  u16x8 cc = ((const u16x8*)c0)[i + 2 * zs];
  u16x8 d = ((const u16x8*)c0)[i + 3 * zs];
  float4 o0, o1;
  o0.x = (bf2f(a[0]) + bf2f(b[0])) + (bf2f(cc[0]) + bf2f(d[0]));
  o0.y = (bf2f(a[1]) + bf2f(b[1])) + (bf2f(cc[1]) + bf2f(d[1]));
  o0.z = (bf2f(a[2]) + bf2f(b[2])) + (bf2f(cc[2]) + bf2f(d[2]));
  o0.w = (bf2f(a[3]) + bf2f(b[3])) + (bf2f(cc[3]) + bf2f(d[3]));
  o1.x = (bf2f(a[4]) + bf2f(b[4])) + (bf2f(cc[4]) + bf2f(d[4]));
  o1.y = (bf2f(a[5]) + bf2f(b[5])) + (bf2f(cc[5]) + bf2f(d[5]));
  o1.z = (bf2f(a[6]) + bf2f(b[6])) + (bf2f(cc[6]) + bf2f(d[6]));
  o1.w = (bf2f(a[7]) + bf2f(b[7])) + (bf2f(cc[7]) + bf2f(d[7]));
  ((float4*)out)[i * 2]     = o0;
  ((float4*)out)[i * 2 + 1] = o1;
}

// --- RoPE for Q (scale*log2e folded in) + GEMM1 3-partial combine; [H][S][D] ---
__global__ void k_ropeq(const u16* __restrict__ qp0, const float* __restrict__ cs,
                        const float* __restrict__ sn, u16* __restrict__ Q) {
  const u16* qp1 = qp0 + (size_t)2048 * 3072;
  const u16* qp2 = qp0 + (size_t)2 * 2048 * 3072;
  int tid = threadIdx.x;
  int idx = blockIdx.x * 4 + (tid >> 6);
  int d = tid & 63;
  int h = idx >> 11, s = idx & (S_ - 1);
  size_t base = (size_t)s * 3072 + h * 128;
  float x1 = bf2f(qp0[base + d]) + bf2f(qp1[base + d]) + bf2f(qp2[base + d]);
  float x2 = bf2f(qp0[base + d + 64]) + bf2f(qp1[base + d + 64]) + bf2f(qp2[base + d + 64]);
  float c1 = cs[s * D_ + d], s1v = sn[s * D_ + d];
  float c2 = cs[s * D_ + d + 64], s2v = sn[s * D_ + d + 64];
  const float sc = 0.12751744422f;  // D^-0.5 * log2(e)  (softmax in log2 domain)
  u16* o = Q + ((size_t)h * S_ + s) * D_;
  o[d]      = f2bf((x1 * c1 - x2 * s1v) * sc);
  o[d + 64] = f2bf((x2 * c2 + x1 * s2v) * sc);
}

// -- RoPE K (row-swizzled) + V transpose (block-swizzled [D][S]) + 3-partial combine --
__global__ void k_ropekv(const u16* __restrict__ qp0, const float* __restrict__ cs,
                         const float* __restrict__ sn, u16* __restrict__ Ksw,
                         u16* __restrict__ Vts) {
  const u16* qp1 = qp0 + (size_t)2048 * 3072;
  const u16* qp2 = qp0 + (size_t)2 * 2048 * 3072;
  int tid = threadIdx.x;
  int idx = blockIdx.x * 4 + (tid >> 6);
  int d = tid & 63;
  int kv = idx >> 11, s = idx & (S_ - 1);
  size_t kb = (size_t)s * 3072 + 2048 + kv * 128;
  size_t vb = kb + 512;
  float x1 = bf2f(qp0[kb + d]) + bf2f(qp1[kb + d]) + bf2f(qp2[kb + d]);
  float x2 = bf2f(qp0[kb + d + 64]) + bf2f(qp1[kb + d + 64]) + bf2f(qp2[kb + d + 64]);
  float v1 = bf2f(qp0[vb + d]) + bf2f(qp1[vb + d]) + bf2f(qp2[vb + d]);
  float v2 = bf2f(qp0[vb + d + 64]) + bf2f(qp1[vb + d + 64]) + bf2f(qp2[vb + d + 64]);
  float c1 = cs[s * D_ + d], s1v = sn[s * D_ + d];
  float c2 = cs[s * D_ + d + 64], s2v = sn[s * D_ + d + 64];
  u16* ko = Ksw + ((size_t)kv * S_ + s) * D_;
  int sw = (s & 7) << 3;
  ko[d ^ sw]        = f2bf(x1 * c1 - x2 * s1v);
  ko[(d + 64) ^ sw] = f2bf(x2 * c2 + x1 * s2v);
  u16* vo = Vts + (size_t)kv * D_ * S_;
  int sc64 = s & ~63, sl = s & 63;
  vo[(size_t)d * S_        + sc64 + (sl ^ ((d & 7) << 3))]        = f2bf(v1);
  vo[(size_t)(d + 64) * S_ + sc64 + (sl ^ (((d + 64) & 7) << 3))] = f2bf(v2);
}

// ------------- retrieval K (row-swizzled) / V^T (block-swizzled) convert -------------
__global__ void k_retr(const float* __restrict__ rk, const float* __restrict__ rv,
                       u16* __restrict__ Krs, u16* __restrict__ Vtrs) {
  int tid = threadIdx.x;
  int idx = blockIdx.x * 2 + (tid >> 7);
  int d = tid & 127;
  int kv = idx >> 11, r = idx & (RLEN_ - 1);
  size_t base = ((size_t)kv * RLEN_ + r) * D_;
  Krs[base + (d ^ ((r & 7) << 3))] = f2bf(rk[base + d]);
  int rc = r & ~63, rl = r & 63;
  Vtrs[((size_t)kv * D_ + d) * RLEN_ + rc + (rl ^ ((d & 7) << 3))] = f2bf(rv[base + d]);
}

// ---- fused attention, 4-HEADS-PER-BLOCK + V dbuf + counted bar2 (R15, kept) ----
__global__ __launch_bounds__(256, 3) void k_attn(
    const u16* __restrict__ Q, const u16* __restrict__ Ksw, const u16* __restrict__ Vts,
    const u16* __restrict__ Krs, const u16* __restrict__ Vtrs,
    u16* __restrict__ Opart, float* __restrict__ Ml) {
  __shared__ __attribute__((aligned(16))) char smem[49152];
  u16* Kl = (u16*)smem;             // 16KB: [64 keys][128 d], row-XOR-swizzled (global pre-swz)
  u16* Vl = (u16*)(smem + 16384);   // 2 x 16KB: [128 d][64 k], col-XOR-swizzled

  const int e = 83 - blockIdx.x, kvh = blockIdx.y, qs = blockIdx.z;  // heavy entries first
  int c, part, np;
  if (e < 7)       { c = e;               part = 0;           np = 1; }
  else if (e < 23) { c = 7 + ((e - 7) >> 1);  part = (e - 7) & 1;  np = 2; }
  else if (e < 47) { c = 15 + (e - 23) / 3;   part = (e - 23) % 3; np = 3; }
  else if (e < 79) { c = 23 + ((e - 47) >> 2); part = (e - 47) & 3; np = 4; }
  else             { c = 31;              part = e - 79;      np = 5; }
  const int nt = (c == 0) ? 1 : (c + 2);
  const int t0 = (part * nt) / np, t1 = ((part + 1) * nt) / np;

  const int tid = threadIdx.x, wave = tid >> 6, lane = tid & 63;
  const int h = kvh * 4 + wave;            // this wave's head
  const int bp = h * 84 + e;
  const int l31 = lane & 31, hf = lane >> 5;
  const int qrow = c * 64 + qs * 32 + l31;

  bf16x8 qf[8];
  {
    const u16* qp = Q + ((size_t)h * S_ + qrow) * D_ + hf * 8;
#pragma unroll
    for (int m = 0; m < 8; m++) qf[m] = *(const bf16x8*)(qp + m * 16);
  }
  float mq = -1e30f, lq = 0.f;
  f32x16 accO[4] = {};   // O^T: accO[dt][reg] = O[d = dt*32+(reg&3)+8*(reg>>2)+4*hf][q=l31]

  const int kgo = (tid >> 4) * 128 + (tid & 15) * 8;   // K: tile-local (row, col8)
  const int vgo = (tid >> 3) * 2048 + (tid & 7) * 8;   // V: (d row)*S + col8 ; S_==RLEN_
  u16* const kdst = Kl + wave * 512;                   // + p*2048

  const int cm1 = (c >= 1) ? (c - 1) : 0;
  const u16* krb = Krs + (size_t)kvh * RLEN_ * D_ + (size_t)cm1 * 64 * D_;
  const u16* vrb = Vtrs + (size_t)kvh * D_ * RLEN_ + cm1 * 64;
  const u16* kst = Ksw + (size_t)kvh * S_ * D_ + (size_t)t0 * 64 * D_;
  const u16* vst = Vts + (size_t)kvh * D_ * S_ + t0 * 64;
  int ts = t0;

#pragma unroll
  for (int p = 0; p < 4; p++) GLL(kst + p * 2048 + kgo, kdst + p * 2048);
#pragma unroll
  for (int p = 0; p < 4; p++) GLL(vst + p * 65536 + vgo, Vl + wave * 512 + p * 2048);
  ts = t0 + 1;
  if (ts == c + 1) { kst = krb; vst = vrb; } else { kst += 64 * D_; vst += 64; }
  drain_then_sync();

  for (int t = t0; t < t1; t++) {
    const int vb = (t - t0) & 1;
    const bool pf = (t + 1 < t1);
    f32x16 sacc[2] = {};
    {
      const char* Kbuf = (const char*)Kl;
#pragma unroll
      for (int kb = 0; kb < 2; kb++)
#pragma unroll
        for (int m = 0; m < 8; m++) {
          int by = ((kb * 32 + l31) << 8) + ((m * 32 + hf * 16) ^ ((l31 & 7) << 4));
          bf16x8 kf = *(const bf16x8*)(Kbuf + by);
          sacc[kb] = __builtin_amdgcn_mfma_f32_32x32x16_bf16(kf, qf[m], sacc[kb], 0, 0, 0);
        }
    }
    drain_then_sync();  // bar1: V(t) proven landed; Kl reads done -> overwritable
    if (pf) {
#pragma unroll
      for (int p = 0; p < 4; p++) GLL(kst + p * 2048 + kgo, kdst + p * 2048);
      u16* vd = Vl + (vb ^ 1) * 8192 + wave * 512;
#pragma unroll
      for (int p = 0; p < 4; p++) GLL(vst + p * 65536 + vgo, vd + p * 2048);
      ts++;
      if (ts == c + 1) { kst = krb; vst = vrb; } else { kst += 64 * D_; vst += 64; }
    }
    if (t == c) {  // diagonal tile causal mask
#pragma unroll
      for (int kb = 0; kb < 2; kb++) {
        const int koffm = kb * 32 - qs * 32;
#pragma unroll
        for (int r = 0; r < 16; r++) {
          int kloc = (r & 3) + 8 * (r >> 2) + 4 * hf + koffm;
          if (kloc > l31) sacc[kb][r] = -1e30f;
        }
      }
    }
    float tmax = sacc[0][0];
#pragma unroll
    for (int r = 1; r < 16; r++) tmax = fmaxf(tmax, sacc[0][r]);
#pragma unroll
    for (int r = 0; r < 16; r++) tmax = fmaxf(tmax, sacc[1][r]);
    tmax = xhalf_max(tmax);
    if (!__all(tmax - mq <= 11.5f)) {  // defer-rescale (T13)
      float mn = fmaxf(mq, tmax);
      float f = exp2v(mq - mn);
      mq = mn; lq *= f;
#pragma unroll
      for (int dt = 0; dt < 4; dt++)
#pragma unroll
        for (int r = 0; r < 16; r++) accO[dt][r] *= f;
    }
    float ps = 0.f;
#pragma unroll
    for (int kb = 0; kb < 2; kb++)
#pragma unroll
      for (int r = 0; r < 16; r++) {
        float p = exp2v(sacc[kb][r] - mq);
        sacc[kb][r] = p; ps += p;
      }
    lq += xhalf_add(ps);
    unsigned W[2][8];
#pragma unroll
    for (int kb = 0; kb < 2; kb++)
#pragma unroll
      for (int g = 0; g < 4; g++) {
        W[kb][2 * g]     = cvtpk(sacc[kb][4 * g],     sacc[kb][4 * g + 1]);
        W[kb][2 * g + 1] = cvtpk(sacc[kb][4 * g + 2], sacc[kb][4 * g + 3]);
      }
    const char* Vbuf = (const char*)(Vl + vb * 8192);
    __builtin_amdgcn_s_setprio(1);
#pragma unroll
    for (int kb = 0; kb < 2; kb++)
#pragma unroll
      for (int st = 0; st < 2; st++) {
        unsigned x0 = W[kb][4 * st], y0 = W[kb][4 * st + 2];
        unsigned x1 = W[kb][4 * st + 1], y1 = W[kb][4 * st + 3];
        pl32swap(x0, y0);
        pl32swap(x1, y1);
        union { unsigned u[4]; bf16x8 v; } pfr;
        pfr.u[0] = x0; pfr.u[1] = x1; pfr.u[2] = y0; pfr.u[3] = y1;
#pragma unroll
        for (int dt = 0; dt < 4; dt++) {
          int vby = ((dt * 32 + l31) << 7) +
                    ((kb * 64 + st * 32 + hf * 16) ^ ((l31 & 7) << 4));
          bf16x8 vf = *(const bf16x8*)(Vbuf + vby);
          accO[dt] = __builtin_amdgcn_mfma_f32_32x32x16_bf16(vf, pfr.v, accO[dt], 0, 0, 0);
        }
      }
    __builtin_amdgcn_s_setprio(0);
    if (pf) drain4_then_sync();  // bar2: K(t+1) (oldest 4 of 8) landed; V(t+1) in flight
  }

  u16* op = Opart + (size_t)bp * 8192 + (size_t)(qs * 32 + l31) * 128;
#pragma unroll
  for (int dt = 0; dt < 4; dt++)
#pragma unroll
    for (int j = 0; j < 4; j++) {
      u16x4 o;
#pragma unroll
      for (int b = 0; b < 4; b++) o[b] = f2bf(accO[dt][4 * j + b]);
      *(u16x4*)(op + dt * 32 + j * 8 + hf * 4) = o;
    }
  if (hf == 0) {
    Ml[(size_t)bp * 128 + qs * 32 + l31]      = mq;
    Ml[(size_t)bp * 128 + 64 + qs * 32 + l31] = lq;
  }
}

// ---------------- split-K combine: merge <=5 partials per (head, chunk); log2 domain ----------------
__global__ __launch_bounds__(256) void k_combine(const u16* __restrict__ Opart,
                                                 const float* __restrict__ Ml,
                                                 u16* __restrict__ attn) {
  const int c = blockIdx.x, h = blockIdx.y;
  const int t = threadIdx.x;
  const int q = t >> 2, d0 = (t & 3) * 32;
  int base, np;
  if (c < 7)       { base = c;                 np = 1; }
  else if (c < 15) { base = 7 + 2 * (c - 7);   np = 2; }
  else if (c < 23) { base = 23 + 3 * (c - 15); np = 3; }
  else if (c < 31) { base = 47 + 4 * (c - 23); np = 4; }
  else             { base = 79;                np = 5; }
  const size_t pb = (size_t)h * 84 + base;

  float m = -1e30f;
  for (int p = 0; p < np; p++) m = fmaxf(m, Ml[(pb + p) * 128 + q]);
  float l = 0.f;
  float N[32];
#pragma unroll
  for (int i = 0; i < 32; i++) N[i] = 0.f;
  for (int p = 0; p < np; p++) {
    const float mp = Ml[(pb + p) * 128 + q];
    const float lp = Ml[(pb + p) * 128 + 64 + q];
    const float w = exp2v(mp - m);
    l += w * lp;
    const u16* op = Opart + (pb + p) * 8192 + q * 128 + d0;
#pragma unroll
    for (int i = 0; i < 4; i++) {
      u16x8 v = ((const u16x8*)op)[i];
#pragma unroll
      for (int ee = 0; ee < 8; ee++) N[i * 8 + ee] += w * bf2f(v[ee]);
    }
  }
  const float inv = 1.f / l;
  u16* dst = attn + (size_t)(c * 64 + q) * (H_ * D_) + h * 128 + d0;
#pragma unroll
  for (int i = 0; i < 4; i++) {
    u16x8 o;
#pragma unroll
    for (int ee = 0; ee < 8; ee++) o[ee] = f2bf(N[i * 8 + ee] * inv);
    ((u16x8*)dst)[i] = o;
  }
}

extern "C" void kernel_launch(void* const* d_in, const int* in_sizes, int n_in,
                              void* d_out, int out_size, void* d_ws, size_t ws_size,
                              hipStream_t stream) {
  const float* hs = (const float*)d_in[0];
  const float* cs = (const float*)d_in[1];
  const float* sn = (const float*)d_in[2];
  const float* rk = (const float*)d_in[3];
  const float* rv = (const float*)d_in[4];
  const float* Wq = (const float*)d_in[5];
  const float* Wk = (const float*)d_in[6];
  const float* Wv = (const float*)d_in[7];
  const float* Wo = (const float*)d_in[8];
  float* out = (float*)d_out;
  char* ws = (char*)d_ws;
  if (ws_size < (size_t)(56u << 20)) return;  // fail visibly (output stays poisoned)

  // ---- workspace choreography (hazard-walked; R10 lesson) ----
  // P1 (cvt/transw_qkv/gemm1): hsb@0..8 | wtq@8..20 | qkvP(3x12MB)@20..56
  u16* hsb  = (u16*)(ws);                 // 8MB  @0
  u16* wtq  = (u16*)(ws + (8u << 20));    // 12MB @8
  u16* qkvP = (u16*)(ws + (20u << 20));   // 36MB @20..56
  // P2 (ropes/retr): read qkvP@20..56 + inputs; write ONLY @0..16 (hsb/wtq dead)
  u16* Qr   = (u16*)(ws);                 // 8MB  @0
  u16* Ks   = (u16*)(ws + (8u << 20));    // 2MB  @8
  u16* Vts  = (u16*)(ws + (10u << 20));   // 2MB  @10
  u16* Krs  = (u16*)(ws + (12u << 20));   // 2MB  @12
  u16* Vtrs = (u16*)(ws + (14u << 20));   // 2MB  @14
  // P3 (transw Wo, AFTER ropes -> qkvP dead): wto@16..24
  u16* wto  = (u16*)(ws + (16u << 20));   // 8MB  @16..24
  // P4 (attn): reads @0..16; writes Opart@24..45, Ml@45..46
  u16* Opart= (u16*)(ws + (24u << 20));   // 21MB @24..45
  float* Ml = (float*)(ws + (45u << 20)); // 0.7MB @45
  // P5 (combine): writes attn@0..8 (Qr dead after attn)
  u16* attn = (u16*)(ws);
  // P6 (gemm2): reads @0..8 + wto@16..24; writes Cp 4x8MB @24..56 (Opart/Ml dead)
  u16* Cp   = (u16*)(ws + (24u << 20));

  dim3 tb(32, 8);
  k_cvt<<<4096, 256, 0, stream>>>(hs, hsb, 1048576);
  k_transw_qkv<<<6144, tb, 0, stream>>>(Wq, Wk, Wv, wtq);
  k_gemm<<<dim3(24, 8, 3), 256, 0, stream>>>(hsb, wtq, qkvP, 2048, 3072, 2048, 672, 32);
  k_ropeq<<<8192, 256, 0, stream>>>(qkvP, cs, sn, Qr);
  k_ropekv<<<2048, 256, 0, stream>>>(qkvP, cs, sn, Ks, Vts);
  k_retr<<<4096, 256, 0, stream>>>(rk, rv, Krs, Vtrs);
  k_transw<<<dim3(64, 64), tb, 0, stream>>>(Wo, wto, 2048, 2048);
  k_attn<<<dim3(84, 4, 2), 256, 0, stream>>>(Qr, Ks, Vts, Krs, Vtrs, Opart, Ml);
  k_combine<<<dim3(32, 16), 256, 0, stream>>>(Opart, Ml, attn);
  k_gemm<<<dim3(16, 8, 4), 256, 0, stream>>>(attn, wto, Cp, 2048, 2048, 2048, 512, 0);
  k_comb4<<<2048, 256, 0, stream>>>(Cp, out, 524288);
}

// Round 17
// 159.082 us; speedup vs baseline: 1.1099x; 1.1099x over previous
//
#include <hip/hip_runtime.h>
#include <stdint.h>

#define H_    16
#define HKV_  4
#define D_    128
#define S_    2048
#define HID_  2048
#define RLEN_ 2048

typedef unsigned short u16;
typedef __attribute__((ext_vector_type(4))) float f32x4;
typedef __attribute__((ext_vector_type(16))) float f32x16;
typedef __attribute__((ext_vector_type(8))) __bf16 bf16x8;
typedef __attribute__((ext_vector_type(4))) unsigned short u16x4;
typedef __attribute__((ext_vector_type(8))) unsigned short u16x8;
typedef __attribute__((ext_vector_type(2))) unsigned int u32x2;

__device__ __forceinline__ u16 f2bf(float f) {
  union { float f; unsigned u; } v; v.f = f;
  unsigned r = v.u + 0x7FFFu + ((v.u >> 16) & 1u);
  return (u16)(r >> 16);
}
__device__ __forceinline__ float bf2f(u16 h) {
  union { unsigned u; float f; } v; v.u = ((unsigned)h) << 16;
  return v.f;
}
__device__ __forceinline__ float exp2v(float x) {  // exact v_exp_f32 (2^x)
  float r; asm("v_exp_f32 %0, %1" : "=v"(r) : "v"(x)); return r;
}
__device__ __forceinline__ unsigned cvtpk(float lo, float hi) {
  unsigned r; asm("v_cvt_pk_bf16_f32 %0, %1, %2" : "=v"(r) : "v"(lo), "v"(hi)); return r;
}
__device__ __forceinline__ void pl32swap(unsigned &a, unsigned &b) {
  u32x2 r = __builtin_amdgcn_permlane32_swap(a, b, false, false);
  a = r.x; b = r.y;  // a' = [a_lo|b_lo], b' = [a_hi|b_hi]
}
__device__ __forceinline__ float xhalf_max(float v) {
  unsigned a = __float_as_uint(v), b = a;
  pl32swap(a, b);
  return fmaxf(__uint_as_float(a), __uint_as_float(b));
}
__device__ __forceinline__ float xhalf_add(float v) {
  unsigned a = __float_as_uint(v), b = a;
  pl32swap(a, b);
  return __uint_as_float(a) + __uint_as_float(b);
}
// Explicit DMA/LDS drain before barriers handing a GLL-target buffer to readers
// (R8 lesson: the compiler's implicit vmcnt(0)-at-barrier is NOT guaranteed).
__device__ __forceinline__ void drain_then_sync() {
  asm volatile("s_waitcnt vmcnt(0) lgkmcnt(0)" ::: "memory");
  __syncthreads();
}
// Counted drain (T4): oldest 4 GLLs proven landed; newest 4 stay in flight.
__device__ __forceinline__ void drain4_then_sync() {
  asm volatile("s_waitcnt vmcnt(4) lgkmcnt(0)" ::: "memory");
  __syncthreads();
}

#define GLL(srcp, ldsp) \
  __builtin_amdgcn_global_load_lds((const __attribute__((address_space(1))) unsigned int*)(srcp), \
                                   (__attribute__((address_space(3))) unsigned int*)(ldsp), 16, 0, 0)

// ---------------- fp32 -> bf16 elementwise ----------------
__global__ void k_cvt(const float* __restrict__ in, u16* __restrict__ out, int n4) {
  int i = blockIdx.x * 256 + threadIdx.x;
  if (i >= n4) return;
  float4 v = ((const float4*)in)[i];
  u16x4 o;
  o.x = f2bf(v.x); o.y = f2bf(v.y); o.z = f2bf(v.z); o.w = f2bf(v.w);
  ((u16x4*)out)[i] = o;
}

// ------- fused Wq|Wk|Wv fp32 (K x N) -> bf16 transposed (N x K); one launch -------
__global__ void k_transw_qkv(const float* __restrict__ Wq, const float* __restrict__ Wk,
                             const float* __restrict__ Wv, u16* __restrict__ wtq) {
  __shared__ float tile[32][33];
  const int bid = blockIdx.x;
  const float* in; u16* out; int N, bx, by;
  if (bid < 4096)      { in = Wq; out = wtq;                          N = 2048; bx = (bid & 63) * 32;        by = (bid >> 6) * 32; }
  else if (bid < 5120) { in = Wk; out = wtq + (size_t)2048 * 2048;    N = 512;  bx = ((bid - 4096) & 15) * 32; by = ((bid - 4096) >> 4) * 32; }
  else                 { in = Wv; out = wtq + (size_t)2560 * 2048;    N = 512;  bx = ((bid - 5120) & 15) * 32; by = ((bid - 5120) >> 4) * 32; }
  const int K = 2048;
  int tx = threadIdx.x, ty = threadIdx.y;  // 32 x 8
#pragma unroll
  for (int i = 0; i < 32; i += 8)
    tile[ty + i][tx] = in[(size_t)(by + ty + i) * N + bx + tx];
  __syncthreads();
#pragma unroll
  for (int i = 0; i < 32; i += 8)
    out[(size_t)(bx + ty + i) * K + by + tx] = f2bf(tile[tx][ty + i]);
}

// ---------------- fp32 (K x N) -> bf16 transposed (N x K) ----------------
__global__ void k_transw(const float* __restrict__ in, u16* __restrict__ out, int K, int N) {
  __shared__ float tile[32][33];
  int bx = blockIdx.x * 32, by = blockIdx.y * 32;
  int tx = threadIdx.x, ty = threadIdx.y;  // 32 x 8
#pragma unroll
  for (int i = 0; i < 32; i += 8)
    tile[ty + i][tx] = in[(size_t)(by + ty + i) * N + bx + tx];
  __syncthreads();
#pragma unroll
  for (int i = 0; i < 32; i += 8)
    out[(size_t)(bx + ty + i) * K + by + tx] = f2bf(tile[tx][ty + i]);
}

// ---- bf16 GEMM (R15 config, best known): 128x128 tile, split-K x Z, 3-buffer
// counted-vmcnt pipeline + T2 LDS swizzle (bank-conflict-free, verified R15) ----
__global__ __launch_bounds__(256) void k_gemm(const u16* __restrict__ A, const u16* __restrict__ Bt,
                                              u16* __restrict__ Cb, int M, int N, int K,
                                              int Kpart, int Krem) {
  __shared__ __attribute__((aligned(16))) u16 As[3][128 * 32];
  __shared__ __attribute__((aligned(16))) u16 Bs[3][128 * 32];
  const int bm = blockIdx.y * 128, bn = blockIdx.x * 128;
  const int kz0 = blockIdx.z * Kpart;
  const int kz1 = kz0 + Kpart + ((blockIdx.z == gridDim.z - 1) ? Krem : 0);
  const int nsteps = (kz1 - kz0) >> 5;
  u16* C = Cb + (size_t)blockIdx.z * M * N;
  const int tid = threadIdx.x, wave = tid >> 6, lane = tid & 63;
  const int wr = wave >> 1, wc = wave & 1;
  const int l15 = lane & 15, lhi = lane >> 4;
  const int so = wave * 512;
  f32x4 acc[4][4] = {};
  // T2: per-lane source col-slot = (tid&3) ^ P(row), P(row)=(row>>1)&3, row=tid>>2
  const int cw = ((tid & 3) ^ ((tid >> 3) & 3)) * 8;
  const u16* pA  = A  + (size_t)(bm + (tid >> 2)) * K + cw;
  const u16* pA2 = A  + (size_t)(bm + 64 + (tid >> 2)) * K + cw;
  const u16* pB  = Bt + (size_t)(bn + (tid >> 2)) * K + cw;
  const u16* pB2 = Bt + (size_t)(bn + 64 + (tid >> 2)) * K + cw;
  // T2 fragment-read slot: lhi ^ P(row), row = *+m*16+l15 -> P=(l15>>1)&3
  const int sc = (lhi ^ ((l15 >> 1) & 3)) * 8;

  auto stage = [&](int s, int buf) {  // 4 GLLs per wave
    const int k0 = kz0 + s * 32;
    GLL(pA + k0,  &As[buf][so]);
    GLL(pA2 + k0, &As[buf][2048 + so]);
    GLL(pB + k0,  &Bs[buf][so]);
    GLL(pB2 + k0, &Bs[buf][2048 + so]);
  };

  stage(0, 0);
  if (nsteps > 1) { stage(1, 1); drain4_then_sync(); }
  else            { drain_then_sync(); }

  for (int s = 0; s < nsteps; s++) {
    const int buf = s % 3;
    const bool deep = (s + 2 < nsteps);
    if (deep) stage(s + 2, (s + 2) % 3);
    bf16x8 af[4], bfr[4];
#pragma unroll
    for (int m = 0; m < 4; m++)
      af[m] = *(const bf16x8*)(&As[buf][(wr * 64 + m * 16 + l15) * 32 + sc]);
#pragma unroll
    for (int n = 0; n < 4; n++)
      bfr[n] = *(const bf16x8*)(&Bs[buf][(wc * 64 + n * 16 + l15) * 32 + sc]);
#pragma unroll
    for (int m = 0; m < 4; m++)
#pragma unroll
      for (int n = 0; n < 4; n++)
        acc[m][n] = __builtin_amdgcn_mfma_f32_16x16x32_bf16(af[m], bfr[n], acc[m][n], 0, 0, 0);
    if (deep) drain4_then_sync();   // L(s+1) landed; L(s+2) stays in flight
    else      drain_then_sync();    // tail: full drain
  }
  const int r0 = bm + wr * 64, c0 = bn + wc * 64;
#pragma unroll
  for (int m = 0; m < 4; m++)
#pragma unroll
    for (int n = 0; n < 4; n++) {
      int r = r0 + m * 16 + lhi * 4, cc = c0 + n * 16 + l15;
#pragma unroll
      for (int j = 0; j < 4; j++)
        C[(size_t)(r + j) * N + cc] = f2bf(acc[m][n][j]);
    }
}

// ---------------- fp32 out = partial0 + partial1 (bf16 partials) ----------------
__global__ void k_comb2(const u16* __restrict__ c0, const u16* __restrict__ c1,
                        float* __restrict__ out, int n8) {
  int i = blockIdx.x * 256 + threadIdx.x;
  if (i >= n8) return;
  u16x8 a = ((const u16x8*)c0)[i];
  u16x8 b = ((const u16x8*)c1)[i];
  float4 o0, o1;
  o0.x = bf2f(a[0]) + bf2f(b[0]); o0.y = bf2f(a[1]) + bf2f(b[1]);
  o0.z = bf2f(a[2]) + bf2f(b[2]); o0.w = bf2f(a[3]) + bf2f(b[3]);
  o1.x = bf2f(a[4]) + bf2f(b[4]); o1.y = bf2f(a[5]) + bf2f(b[5]);
  o1.z = bf2f(a[6]) + bf2f(b[6]); o1.w = bf2f(a[7]) + bf2f(b[7]);
  ((float4*)out)[i * 2]     = o0;
  ((float4*)out)[i * 2 + 1] = o1;
}

// --- RoPE for Q (scale*log2e folded in) + GEMM1 2-partial combine; [H][S][D] ---
__global__ void k_ropeq(const u16* __restrict__ qp0, const float* __restrict__ cs,
                        const float* __restrict__ sn, u16* __restrict__ Q) {
  const u16* qp1 = qp0 + (size_t)2048 * 3072;
  int tid = threadIdx.x;
  int idx = blockIdx.x * 4 + (tid >> 6);
  int d = tid & 63;
  int h = idx >> 11, s = idx & (S_ - 1);
  size_t base = (size_t)s * 3072 + h * 128;
  float x1 = bf2f(qp0[base + d])      + bf2f(qp1[base + d]);
  float x2 = bf2f(qp0[base + d + 64]) + bf2f(qp1[base + d + 64]);
  float c1 = cs[s * D_ + d], s1v = sn[s * D_ + d];
  float c2 = cs[s * D_ + d + 64], s2v = sn[s * D_ + d + 64];
  const float sc = 0.12751744422f;  // D^-0.5 * log2(e)  (softmax in log2 domain)
  u16* o = Q + ((size_t)h * S_ + s) * D_;
  o[d]      = f2bf((x1 * c1 - x2 * s1v) * sc);
  o[d + 64] = f2bf((x2 * c2 + x1 * s2v) * sc);
}

// -- RoPE K (row-swizzled) + V transpose (block-swizzled [D][S]) + 2-partial combine --
__global__ void k_ropekv(const u16* __restrict__ qp0, const float* __restrict__ cs,
                         const float* __restrict__ sn, u16* __restrict__ Ksw,
                         u16* __restrict__ Vts) {
  const u16* qp1 = qp0 + (size_t)2048 * 3072;
  int tid = threadIdx.x;
  int idx = blockIdx.x * 4 + (tid >> 6);
  int d = tid & 63;
  int kv = idx >> 11, s = idx & (S_ - 1);
  size_t kb = (size_t)s * 3072 + 2048 + kv * 128;
  size_t vb = kb + 512;
  float x1 = bf2f(qp0[kb + d])      + bf2f(qp1[kb + d]);
  float x2 = bf2f(qp0[kb + d + 64]) + bf2f(qp1[kb + d + 64]);
  float v1 = bf2f(qp0[vb + d])      + bf2f(qp1[vb + d]);
  float v2 = bf2f(qp0[vb + d + 64]) + bf2f(qp1[vb + d + 64]);
  float c1 = cs[s * D_ + d], s1v = sn[s * D_ + d];
  float c2 = cs[s * D_ + d + 64], s2v = sn[s * D_ + d + 64];
  u16* ko = Ksw + ((size_t)kv * S_ + s) * D_;
  int sw = (s & 7) << 3;
  ko[d ^ sw]        = f2bf(x1 * c1 - x2 * s1v);
  ko[(d + 64) ^ sw] = f2bf(x2 * c2 + x1 * s2v);
  u16* vo = Vts + (size_t)kv * D_ * S_;
  int sc64 = s & ~63, sl = s & 63;
  vo[(size_t)d * S_        + sc64 + (sl ^ ((d & 7) << 3))]        = f2bf(v1);
  vo[(size_t)(d + 64) * S_ + sc64 + (sl ^ (((d + 64) & 7) << 3))] = f2bf(v2);
}

// ------------- retrieval K (row-swizzled) / V^T (block-swizzled) convert -------------
__global__ void k_retr(const float* __restrict__ rk, const float* __restrict__ rv,
                       u16* __restrict__ Krs, u16* __restrict__ Vtrs) {
  int tid = threadIdx.x;
  int idx = blockIdx.x * 2 + (tid >> 7);
  int d = tid & 127;
  int kv = idx >> 11, r = idx & (RLEN_ - 1);
  size_t base = ((size_t)kv * RLEN_ + r) * D_;
  Krs[base + (d ^ ((r & 7) << 3))] = f2bf(rk[base + d]);
  int rc = r & ~63, rl = r & 63;
  Vtrs[((size_t)kv * D_ + d) * RLEN_ + rc + (rl ^ ((d & 7) << 3))] = f2bf(rv[base + d]);
}

// ---- fused attention, 4-HEADS-PER-BLOCK + V double-buffer + counted bar2 (R15) ----
__global__ __launch_bounds__(256, 3) void k_attn(
    const u16* __restrict__ Q, const u16* __restrict__ Ksw, const u16* __restrict__ Vts,
    const u16* __restrict__ Krs, const u16* __restrict__ Vtrs,
    u16* __restrict__ Opart, float* __restrict__ Ml) {
  __shared__ __attribute__((aligned(16))) char smem[49152];
  u16* Kl = (u16*)smem;             // 16KB: [64 keys][128 d], row-XOR-swizzled (global pre-swz)
  u16* Vl = (u16*)(smem + 16384);   // 2 x 16KB: [128 d][64 k], col-XOR-swizzled

  const int e = 83 - blockIdx.x, kvh = blockIdx.y, qs = blockIdx.z;  // heavy entries first
  int c, part, np;
  if (e < 7)       { c = e;               part = 0;           np = 1; }
  else if (e < 23) { c = 7 + ((e - 7) >> 1);  part = (e - 7) & 1;  np = 2; }
  else if (e < 47) { c = 15 + (e - 23) / 3;   part = (e - 23) % 3; np = 3; }
  else if (e < 79) { c = 23 + ((e - 47) >> 2); part = (e - 47) & 3; np = 4; }
  else             { c = 31;              part = e - 79;      np = 5; }
  const int nt = (c == 0) ? 1 : (c + 2);
  const int t0 = (part * nt) / np, t1 = ((part + 1) * nt) / np;

  const int tid = threadIdx.x, wave = tid >> 6, lane = tid & 63;
  const int h = kvh * 4 + wave;            // this wave's head
  const int bp = h * 84 + e;
  const int l31 = lane & 31, hf = lane >> 5;
  const int qrow = c * 64 + qs * 32 + l31;

  bf16x8 qf[8];
  {
    const u16* qp = Q + ((size_t)h * S_ + qrow) * D_ + hf * 8;
#pragma unroll
    for (int m = 0; m < 8; m++) qf[m] = *(const bf16x8*)(qp + m * 16);
  }
  float mq = -1e30f, lq = 0.f;
  f32x16 accO[4] = {};   // O^T: accO[dt][reg] = O[d = dt*32+(reg&3)+8*(reg>>2)+4*hf][q=l31]

  const int kgo = (tid >> 4) * 128 + (tid & 15) * 8;   // K: tile-local (row, col8)
  const int vgo = (tid >> 3) * 2048 + (tid & 7) * 8;   // V: (d row)*S + col8 ; S_==RLEN_
  u16* const kdst = Kl + wave * 512;                   // + p*2048

  const int cm1 = (c >= 1) ? (c - 1) : 0;
  const u16* krb = Krs + (size_t)kvh * RLEN_ * D_ + (size_t)cm1 * 64 * D_;
  const u16* vrb = Vtrs + (size_t)kvh * D_ * RLEN_ + cm1 * 64;
  const u16* kst = Ksw + (size_t)kvh * S_ * D_ + (size_t)t0 * 64 * D_;
  const u16* vst = Vts + (size_t)kvh * D_ * S_ + t0 * 64;
  int ts = t0;

#pragma unroll
  for (int p = 0; p < 4; p++) GLL(kst + p * 2048 + kgo, kdst + p * 2048);
#pragma unroll
  for (int p = 0; p < 4; p++) GLL(vst + p * 65536 + vgo, Vl + wave * 512 + p * 2048);
  ts = t0 + 1;
  if (ts == c + 1) { kst = krb; vst = vrb; } else { kst += 64 * D_; vst += 64; }
  drain_then_sync();

  for (int t = t0; t < t1; t++) {
    const int vb = (t - t0) & 1;
    const bool pf = (t + 1 < t1);
    f32x16 sacc[2] = {};
    {
      const char* Kbuf = (const char*)Kl;
#pragma unroll
      for (int kb = 0; kb < 2; kb++)
#pragma unroll
        for (int m = 0; m < 8; m++) {
          int by = ((kb * 32 + l31) << 8) + ((m * 32 + hf * 16) ^ ((l31 & 7) << 4));
          bf16x8 kf = *(const bf16x8*)(Kbuf + by);
          sacc[kb] = __builtin_amdgcn_mfma_f32_32x32x16_bf16(kf, qf[m], sacc[kb], 0, 0, 0);
        }
    }
    drain_then_sync();  // bar1: V(t) proven landed; Kl reads done -> overwritable
    if (pf) {
#pragma unroll
      for (int p = 0; p < 4; p++) GLL(kst + p * 2048 + kgo, kdst + p * 2048);
      u16* vd = Vl + (vb ^ 1) * 8192 + wave * 512;
#pragma unroll
      for (int p = 0; p < 4; p++) GLL(vst + p * 65536 + vgo, vd + p * 2048);
      ts++;
      if (ts == c + 1) { kst = krb; vst = vrb; } else { kst += 64 * D_; vst += 64; }
    }
    if (t == c) {  // diagonal tile causal mask: key kb*32+kloc > q qs*32+l31
#pragma unroll
      for (int kb = 0; kb < 2; kb++) {
        const int koffm = kb * 32 - qs * 32;
#pragma unroll
        for (int r = 0; r < 16; r++) {
          int kloc = (r & 3) + 8 * (r >> 2) + 4 * hf + koffm;
          if (kloc > l31) sacc[kb][r] = -1e30f;
        }
      }
    }
    float tmax = sacc[0][0];
#pragma unroll
    for (int r = 1; r < 16; r++) tmax = fmaxf(tmax, sacc[0][r]);
#pragma unroll
    for (int r = 0; r < 16; r++) tmax = fmaxf(tmax, sacc[1][r]);
    tmax = xhalf_max(tmax);
    if (!__all(tmax - mq <= 11.5f)) {  // defer-rescale (T13)
      float mn = fmaxf(mq, tmax);
      float f = exp2v(mq - mn);
      mq = mn; lq *= f;
#pragma unroll
      for (int dt = 0; dt < 4; dt++)
#pragma unroll
        for (int r = 0; r < 16; r++) accO[dt][r] *= f;
    }
    float ps = 0.f;
#pragma unroll
    for (int kb = 0; kb < 2; kb++)
#pragma unroll
      for (int r = 0; r < 16; r++) {
        float p = exp2v(sacc[kb][r] - mq);
        sacc[kb][r] = p; ps += p;
      }
    lq += xhalf_add(ps);
    unsigned W[2][8];
#pragma unroll
    for (int kb = 0; kb < 2; kb++)
#pragma unroll
      for (int g = 0; g < 4; g++) {
        W[kb][2 * g]     = cvtpk(sacc[kb][4 * g],     sacc[kb][4 * g + 1]);
        W[kb][2 * g + 1] = cvtpk(sacc[kb][4 * g + 2], sacc[kb][4 * g + 3]);
      }
    const char* Vbuf = (const char*)(Vl + vb * 8192);
    __builtin_amdgcn_s_setprio(1);
#pragma unroll
    for (int kb = 0; kb < 2; kb++)
#pragma unroll
      for (int st = 0; st < 2; st++) {
        unsigned x0 = W[kb][4 * st], y0 = W[kb][4 * st + 2];
        unsigned x1 = W[kb][4 * st + 1], y1 = W[kb][4 * st + 3];
        pl32swap(x0, y0);
        pl32swap(x1, y1);
        union { unsigned u[4]; bf16x8 v; } pfr;
        pfr.u[0] = x0; pfr.u[1] = x1; pfr.u[2] = y0; pfr.u[3] = y1;
#pragma unroll
        for (int dt = 0; dt < 4; dt++) {
          int vby = ((dt * 32 + l31) << 7) +
                    ((kb * 64 + st * 32 + hf * 16) ^ ((l31 & 7) << 4));
          bf16x8 vf = *(const bf16x8*)(Vbuf + vby);
          accO[dt] = __builtin_amdgcn_mfma_f32_32x32x16_bf16(vf, pfr.v, accO[dt], 0, 0, 0);
        }
      }
    __builtin_amdgcn_s_setprio(0);
    if (pf) drain4_then_sync();  // bar2: K(t+1) (oldest 4 of 8) landed; V(t+1) in flight
  }

  u16* op = Opart + (size_t)bp * 8192 + (size_t)(qs * 32 + l31) * 128;
#pragma unroll
  for (int dt = 0; dt < 4; dt++)
#pragma unroll
    for (int j = 0; j < 4; j++) {
      u16x4 o;
#pragma unroll
      for (int b = 0; b < 4; b++) o[b] = f2bf(accO[dt][4 * j + b]);
      *(u16x4*)(op + dt * 32 + j * 8 + hf * 4) = o;
    }
  if (hf == 0) {
    Ml[(size_t)bp * 128 + qs * 32 + l31]      = mq;
    Ml[(size_t)bp * 128 + 64 + qs * 32 + l31] = lq;
  }
}

// ---------------- split-K combine: merge <=5 partials per (head, chunk); log2 domain ----------------
__global__ __launch_bounds__(256) void k_combine(const u16* __restrict__ Opart,
                                                 const float* __restrict__ Ml,
                                                 u16* __restrict__ attn) {
  const int c = blockIdx.x, h = blockIdx.y;
  const int t = threadIdx.x;
  const int q = t >> 2, d0 = (t & 3) * 32;
  int base, np;
  if (c < 7)       { base = c;                 np = 1; }
  else if (c < 15) { base = 7 + 2 * (c - 7);   np = 2; }
  else if (c < 23) { base = 23 + 3 * (c - 15); np = 3; }
  else if (c < 31) { base = 47 + 4 * (c - 23); np = 4; }
  else             { base = 79;                np = 5; }
  const size_t pb = (size_t)h * 84 + base;

  float m = -1e30f;
  for (int p = 0; p < np; p++) m = fmaxf(m, Ml[(pb + p) * 128 + q]);
  float l = 0.f;
  float N[32];
#pragma unroll
  for (int i = 0; i < 32; i++) N[i] = 0.f;
  for (int p = 0; p < np; p++) {
    const float mp = Ml[(pb + p) * 128 + q];
    const float lp = Ml[(pb + p) * 128 + 64 + q];
    const float w = exp2v(mp - m);
    l += w * lp;
    const u16* op = Opart + (pb + p) * 8192 + q * 128 + d0;
#pragma unroll
    for (int i = 0; i < 4; i++) {
      u16x8 v = ((const u16x8*)op)[i];
#pragma unroll
      for (int ee = 0; ee < 8; ee++) N[i * 8 + ee] += w * bf2f(v[ee]);
    }
  }
  const float inv = 1.f / l;
  u16* dst = attn + (size_t)(c * 64 + q) * (H_ * D_) + h * 128 + d0;
#pragma unroll
  for (int i = 0; i < 4; i++) {
    u16x8 o;
#pragma unroll
    for (int ee = 0; ee < 8; ee++) o[ee] = f2bf(N[i * 8 + ee] * inv);
    ((u16x8*)dst)[i] = o;
  }
}

extern "C" void kernel_launch(void* const* d_in, const int* in_sizes, int n_in,
                              void* d_out, int out_size, void* d_ws, size_t ws_size,
                              hipStream_t stream) {
  const float* hs = (const float*)d_in[0];
  const float* cs = (const float*)d_in[1];
  const float* sn = (const float*)d_in[2];
  const float* rk = (const float*)d_in[3];
  const float* rv = (const float*)d_in[4];
  const float* Wq = (const float*)d_in[5];
  const float* Wk = (const float*)d_in[6];
  const float* Wv = (const float*)d_in[7];
  const float* Wo = (const float*)d_in[8];
  float* out = (float*)d_out;
  char* ws = (char*)d_ws;
  if (ws_size < (size_t)(56u << 20)) return;  // fail visibly (output stays poisoned)

  // ---- workspace choreography (hazard-walked per launch; R10 lesson) ----
  // phase-1: hsb@0..8 | wtq@8..20 | qkvP@20..44 (2x12MB bf16 partials)
  u16* hsb  = (u16*)(ws);                 // 8MB  @0
  u16* wtq  = (u16*)(ws + (8u << 20));    // 12MB @8
  u16* qkvP = (u16*)(ws + (20u << 20));   // 24MB @20
  // phase-2: ropes read qkvP@20..44, write @44..56 (disjoint); retr/wto fill dead wtq@8..20
  u16* Qr   = (u16*)(ws + (44u << 20));   // 8MB  @44
  u16* Ks   = (u16*)(ws + (52u << 20));   // 2MB  @52
  u16* Vts  = (u16*)(ws + (54u << 20));   // 2MB  @54
  u16* Krs  = (u16*)(ws + (8u << 20));    // 2MB  @8   (after gemm1; dead wtq)
  u16* Vtrs = (u16*)(ws + (10u << 20));   // 2MB  @10
  u16* wto  = (u16*)(ws + (12u << 20));   // 8MB  @12..20
  // k_attn: reads @44..56, @8..12; writes Opart@20..41, Ml@41..42 (qkvP dead after ropes)
  u16* Opart= (u16*)(ws + (20u << 20));   // 21MB @20..41
  float* Ml = (float*)(ws + (41u << 20)); // 0.7MB @41
  // phase-3: attn@0..8 (hsb dead); Cp@20..36 2x8MB bf16 (Opart dead after combine)
  u16* attn = (u16*)(ws);
  u16* Cp   = (u16*)(ws + (20u << 20));

  dim3 tb(32, 8);
  k_cvt<<<4096, 256, 0, stream>>>(hs, hsb, 1048576);
  k_transw_qkv<<<6144, tb, 0, stream>>>(Wq, Wk, Wv, wtq);
  k_gemm<<<dim3(24, 16, 2), 256, 0, stream>>>(hsb, wtq, qkvP, 2048, 3072, 2048, 1024, 0);
  k_ropeq<<<8192, 256, 0, stream>>>(qkvP, cs, sn, Qr);
  k_ropekv<<<2048, 256, 0, stream>>>(qkvP, cs, sn, Ks, Vts);
  k_retr<<<4096, 256, 0, stream>>>(rk, rv, Krs, Vtrs);
  k_transw<<<dim3(64, 64), tb, 0, stream>>>(Wo, wto, 2048, 2048);
  k_attn<<<dim3(84, 4, 2), 256, 0, stream>>>(Qr, Ks, Vts, Krs, Vtrs, Opart, Ml);
  k_combine<<<dim3(32, 16), 256, 0, stream>>>(Opart, Ml, attn);
  k_gemm<<<dim3(16, 16, 2), 256, 0, stream>>>(attn, wto, Cp, 2048, 2048, 2048, 1024, 0);
  k_comb2<<<2048, 256, 0, stream>>>(Cp, Cp + (size_t)2048 * 2048, out, 524288);
}

// Round 18
// 146.618 us; speedup vs baseline: 1.2043x; 1.0850x over previous
//
#include <hip/hip_runtime.h>
#include <stdint.h>

#define H_    16
#define HKV_  4
#define D_    128
#define S_    2048
#define HID_  2048
#define RLEN_ 2048

typedef unsigned short u16;
typedef __attribute__((ext_vector_type(4))) float f32x4;
typedef __attribute__((ext_vector_type(16))) float f32x16;
typedef __attribute__((ext_vector_type(8))) __bf16 bf16x8;
typedef __attribute__((ext_vector_type(4))) unsigned short u16x4;
typedef __attribute__((ext_vector_type(8))) unsigned short u16x8;
typedef __attribute__((ext_vector_type(2))) unsigned int u32x2;

__device__ __forceinline__ u16 f2bf(float f) {
  union { float f; unsigned u; } v; v.f = f;
  unsigned r = v.u + 0x7FFFu + ((v.u >> 16) & 1u);
  return (u16)(r >> 16);
}
__device__ __forceinline__ float bf2f(u16 h) {
  union { unsigned u; float f; } v; v.u = ((unsigned)h) << 16;
  return v.f;
}
__device__ __forceinline__ float exp2v(float x) {  // exact v_exp_f32 (2^x)
  float r; asm("v_exp_f32 %0, %1" : "=v"(r) : "v"(x)); return r;
}
__device__ __forceinline__ unsigned cvtpk(float lo, float hi) {
  unsigned r; asm("v_cvt_pk_bf16_f32 %0, %1, %2" : "=v"(r) : "v"(lo), "v"(hi)); return r;
}
__device__ __forceinline__ void pl32swap(unsigned &a, unsigned &b) {
  u32x2 r = __builtin_amdgcn_permlane32_swap(a, b, false, false);
  a = r.x; b = r.y;  // a' = [a_lo|b_lo], b' = [a_hi|b_hi]
}
__device__ __forceinline__ float xhalf_max(float v) {
  unsigned a = __float_as_uint(v), b = a;
  pl32swap(a, b);
  return fmaxf(__uint_as_float(a), __uint_as_float(b));
}
__device__ __forceinline__ float xhalf_add(float v) {
  unsigned a = __float_as_uint(v), b = a;
  pl32swap(a, b);
  return __uint_as_float(a) + __uint_as_float(b);
}
// Explicit DMA/LDS drain before barriers handing a GLL-target buffer to readers
// (R8 lesson: the compiler's implicit vmcnt(0)-at-barrier is NOT guaranteed).
__device__ __forceinline__ void drain_then_sync() {
  asm volatile("s_waitcnt vmcnt(0) lgkmcnt(0)" ::: "memory");
  __syncthreads();
}
// Counted drain (T4): oldest 4 GLLs proven landed; newest 4 stay in flight.
__device__ __forceinline__ void drain4_then_sync() {
  asm volatile("s_waitcnt vmcnt(4) lgkmcnt(0)" ::: "memory");
  __syncthreads();
}

#define GLL(srcp, ldsp) \
  __builtin_amdgcn_global_load_lds((const __attribute__((address_space(1))) unsigned int*)(srcp), \
                                   (__attribute__((address_space(3))) unsigned int*)(ldsp), 16, 0, 0)

// ---- fused prep1: hs fp32->bf16 (blocks 0..4095) + Wq|Wk|Wv transpose (4096..10239) ----
__global__ void k_prep1(const float* __restrict__ hs, const float* __restrict__ Wq,
                        const float* __restrict__ Wk, const float* __restrict__ Wv,
                        u16* __restrict__ hsb, u16* __restrict__ wtq) {
  __shared__ float tile[32][33];
  const int bid = blockIdx.x, tid = threadIdx.x;
  if (bid < 4096) {  // cvt: 1048576 float4
    int i = bid * 256 + tid;
    float4 v = ((const float4*)hs)[i];
    u16x4 o;
    o.x = f2bf(v.x); o.y = f2bf(v.y); o.z = f2bf(v.z); o.w = f2bf(v.w);
    ((u16x4*)hsb)[i] = o;
    return;
  }
  const int b = bid - 4096;
  const float* in; u16* out; int N, bx, by;
  if (b < 4096)      { in = Wq; out = wtq;                          N = 2048; bx = (b & 63) * 32;          by = (b >> 6) * 32; }
  else if (b < 5120) { in = Wk; out = wtq + (size_t)2048 * 2048;    N = 512;  bx = ((b - 4096) & 15) * 32; by = ((b - 4096) >> 4) * 32; }
  else               { in = Wv; out = wtq + (size_t)2560 * 2048;    N = 512;  bx = ((b - 5120) & 15) * 32; by = ((b - 5120) >> 4) * 32; }
  const int K = 2048;
  int tx = tid & 31, ty = tid >> 5;  // 32 x 8
#pragma unroll
  for (int i = 0; i < 32; i += 8)
    tile[ty + i][tx] = in[(size_t)(by + ty + i) * N + bx + tx];
  __syncthreads();
#pragma unroll
  for (int i = 0; i < 32; i += 8)
    out[(size_t)(bx + ty + i) * K + by + tx] = f2bf(tile[tx][ty + i]);
}

// ---- bf16 GEMM (R15 config, best known): 128x128 tile, split-K x Z, 3-buffer
// counted-vmcnt pipeline + T2 LDS swizzle (bank-conflict-free, verified R15) ----
__global__ __launch_bounds__(256) void k_gemm(const u16* __restrict__ A, const u16* __restrict__ Bt,
                                              u16* __restrict__ Cb, int M, int N, int K,
                                              int Kpart, int Krem) {
  __shared__ __attribute__((aligned(16))) u16 As[3][128 * 32];
  __shared__ __attribute__((aligned(16))) u16 Bs[3][128 * 32];
  const int bm = blockIdx.y * 128, bn = blockIdx.x * 128;
  const int kz0 = blockIdx.z * Kpart;
  const int kz1 = kz0 + Kpart + ((blockIdx.z == gridDim.z - 1) ? Krem : 0);
  const int nsteps = (kz1 - kz0) >> 5;
  u16* C = Cb + (size_t)blockIdx.z * M * N;
  const int tid = threadIdx.x, wave = tid >> 6, lane = tid & 63;
  const int wr = wave >> 1, wc = wave & 1;
  const int l15 = lane & 15, lhi = lane >> 4;
  const int so = wave * 512;
  f32x4 acc[4][4] = {};
  // T2: per-lane source col-slot = (tid&3) ^ P(row), P(row)=(row>>1)&3, row=tid>>2
  const int cw = ((tid & 3) ^ ((tid >> 3) & 3)) * 8;
  const u16* pA  = A  + (size_t)(bm + (tid >> 2)) * K + cw;
  const u16* pA2 = A  + (size_t)(bm + 64 + (tid >> 2)) * K + cw;
  const u16* pB  = Bt + (size_t)(bn + (tid >> 2)) * K + cw;
  const u16* pB2 = Bt + (size_t)(bn + 64 + (tid >> 2)) * K + cw;
  // T2 fragment-read slot: lhi ^ P(row), row = *+m*16+l15 -> P=(l15>>1)&3
  const int sc = (lhi ^ ((l15 >> 1) & 3)) * 8;

  auto stage = [&](int s, int buf) {  // 4 GLLs per wave
    const int k0 = kz0 + s * 32;
    GLL(pA + k0,  &As[buf][so]);
    GLL(pA2 + k0, &As[buf][2048 + so]);
    GLL(pB + k0,  &Bs[buf][so]);
    GLL(pB2 + k0, &Bs[buf][2048 + so]);
  };

  stage(0, 0);
  if (nsteps > 1) { stage(1, 1); drain4_then_sync(); }
  else            { drain_then_sync(); }

  for (int s = 0; s < nsteps; s++) {
    const int buf = s % 3;
    const bool deep = (s + 2 < nsteps);
    if (deep) stage(s + 2, (s + 2) % 3);
    bf16x8 af[4], bfr[4];
#pragma unroll
    for (int m = 0; m < 4; m++)
      af[m] = *(const bf16x8*)(&As[buf][(wr * 64 + m * 16 + l15) * 32 + sc]);
#pragma unroll
    for (int n = 0; n < 4; n++)
      bfr[n] = *(const bf16x8*)(&Bs[buf][(wc * 64 + n * 16 + l15) * 32 + sc]);
#pragma unroll
    for (int m = 0; m < 4; m++)
#pragma unroll
      for (int n = 0; n < 4; n++)
        acc[m][n] = __builtin_amdgcn_mfma_f32_16x16x32_bf16(af[m], bfr[n], acc[m][n], 0, 0, 0);
    if (deep) drain4_then_sync();   // L(s+1) landed; L(s+2) stays in flight
    else      drain_then_sync();    // tail: full drain
  }
  const int r0 = bm + wr * 64, c0 = bn + wc * 64;
#pragma unroll
  for (int m = 0; m < 4; m++)
#pragma unroll
    for (int n = 0; n < 4; n++) {
      int r = r0 + m * 16 + lhi * 4, cc = c0 + n * 16 + l15;
#pragma unroll
      for (int j = 0; j < 4; j++)
        C[(size_t)(r + j) * N + cc] = f2bf(acc[m][n][j]);
    }
}

// ---------------- fp32 out = partial0 + partial1 (bf16 partials) ----------------
__global__ void k_comb2(const u16* __restrict__ c0, const u16* __restrict__ c1,
                        float* __restrict__ out, int n8) {
  int i = blockIdx.x * 256 + threadIdx.x;
  if (i >= n8) return;
  u16x8 a = ((const u16x8*)c0)[i];
  u16x8 b = ((const u16x8*)c1)[i];
  float4 o0, o1;
  o0.x = bf2f(a[0]) + bf2f(b[0]); o0.y = bf2f(a[1]) + bf2f(b[1]);
  o0.z = bf2f(a[2]) + bf2f(b[2]); o0.w = bf2f(a[3]) + bf2f(b[3]);
  o1.x = bf2f(a[4]) + bf2f(b[4]); o1.y = bf2f(a[5]) + bf2f(b[5]);
  o1.z = bf2f(a[6]) + bf2f(b[6]); o1.w = bf2f(a[7]) + bf2f(b[7]);
  ((float4*)out)[i * 2]     = o0;
  ((float4*)out)[i * 2 + 1] = o1;
}

// ---- fused prep2: ropeq (0..8191) + ropekv (8192..10239) + retrieval convert
//      (10240..14335) + Wo transpose (14336..18431); all parts independent,
//      write regions disjoint (hazard-walked R17/R18) ----
__global__ void k_prep2(const u16* __restrict__ qp0, const float* __restrict__ cs,
                        const float* __restrict__ sn, const float* __restrict__ rk,
                        const float* __restrict__ rv, const float* __restrict__ Wo,
                        u16* __restrict__ Q, u16* __restrict__ Ksw, u16* __restrict__ Vts,
                        u16* __restrict__ Krs, u16* __restrict__ Vtrs, u16* __restrict__ wto) {
  __shared__ float tile[32][33];
  const int bid = blockIdx.x, tid = threadIdx.x;
  const u16* qp1 = qp0 + (size_t)2048 * 3072;
  if (bid < 8192) {  // ropeq: scale*log2e folded; [H][S][D]
    int idx = bid * 4 + (tid >> 6);
    int d = tid & 63;
    int h = idx >> 11, s = idx & (S_ - 1);
    size_t base = (size_t)s * 3072 + h * 128;
    float x1 = bf2f(qp0[base + d])      + bf2f(qp1[base + d]);
    float x2 = bf2f(qp0[base + d + 64]) + bf2f(qp1[base + d + 64]);
    float c1 = cs[s * D_ + d], s1v = sn[s * D_ + d];
    float c2 = cs[s * D_ + d + 64], s2v = sn[s * D_ + d + 64];
    const float sc = 0.12751744422f;  // D^-0.5 * log2(e)
    u16* o = Q + ((size_t)h * S_ + s) * D_;
    o[d]      = f2bf((x1 * c1 - x2 * s1v) * sc);
    o[d + 64] = f2bf((x2 * c2 + x1 * s2v) * sc);
    return;
  }
  if (bid < 10240) {  // ropekv: K row-swizzled + V transpose block-swizzled
    int idx = (bid - 8192) * 4 + (tid >> 6);
    int d = tid & 63;
    int kv = idx >> 11, s = idx & (S_ - 1);
    size_t kb = (size_t)s * 3072 + 2048 + kv * 128;
    size_t vb = kb + 512;
    float x1 = bf2f(qp0[kb + d])      + bf2f(qp1[kb + d]);
    float x2 = bf2f(qp0[kb + d + 64]) + bf2f(qp1[kb + d + 64]);
    float v1 = bf2f(qp0[vb + d])      + bf2f(qp1[vb + d]);
    float v2 = bf2f(qp0[vb + d + 64]) + bf2f(qp1[vb + d + 64]);
    float c1 = cs[s * D_ + d], s1v = sn[s * D_ + d];
    float c2 = cs[s * D_ + d + 64], s2v = sn[s * D_ + d + 64];
    u16* ko = Ksw + ((size_t)kv * S_ + s) * D_;
    int sw = (s & 7) << 3;
    ko[d ^ sw]        = f2bf(x1 * c1 - x2 * s1v);
    ko[(d + 64) ^ sw] = f2bf(x2 * c2 + x1 * s2v);
    u16* vo = Vts + (size_t)kv * D_ * S_;
    int sc64 = s & ~63, sl = s & 63;
    vo[(size_t)d * S_        + sc64 + (sl ^ ((d & 7) << 3))]        = f2bf(v1);
    vo[(size_t)(d + 64) * S_ + sc64 + (sl ^ (((d + 64) & 7) << 3))] = f2bf(v2);
    return;
  }
  if (bid < 14336) {  // retrieval K (row-swizzled) / V^T (block-swizzled)
    int idx = (bid - 10240) * 2 + (tid >> 7);
    int d = tid & 127;
    int kv = idx >> 11, r = idx & (RLEN_ - 1);
    size_t base = ((size_t)kv * RLEN_ + r) * D_;
    Krs[base + (d ^ ((r & 7) << 3))] = f2bf(rk[base + d]);
    int rc = r & ~63, rl = r & 63;
    Vtrs[((size_t)kv * D_ + d) * RLEN_ + rc + (rl ^ ((d & 7) << 3))] = f2bf(rv[base + d]);
    return;
  }
  // Wo transpose: fp32 (2048 x 2048) -> bf16 transposed
  {
    const int b = bid - 14336;
    const int bx = (b & 63) * 32, by = (b >> 6) * 32;
    const int N = 2048, K = 2048;
    int tx = tid & 31, ty = tid >> 5;
#pragma unroll
    for (int i = 0; i < 32; i += 8)
      tile[ty + i][tx] = Wo[(size_t)(by + ty + i) * N + bx + tx];
    __syncthreads();
#pragma unroll
    for (int i = 0; i < 32; i += 8)
      wto[(size_t)(bx + ty + i) * K + by + tx] = f2bf(tile[tx][ty + i]);
  }
}

// ---- fused attention, 4-HEADS-PER-BLOCK + V double-buffer + counted bar2 (R15) ----
__global__ __launch_bounds__(256, 3) void k_attn(
    const u16* __restrict__ Q, const u16* __restrict__ Ksw, const u16* __restrict__ Vts,
    const u16* __restrict__ Krs, const u16* __restrict__ Vtrs,
    u16* __restrict__ Opart, float* __restrict__ Ml) {
  __shared__ __attribute__((aligned(16))) char smem[49152];
  u16* Kl = (u16*)smem;             // 16KB: [64 keys][128 d], row-XOR-swizzled (global pre-swz)
  u16* Vl = (u16*)(smem + 16384);   // 2 x 16KB: [128 d][64 k], col-XOR-swizzled

  const int e = 83 - blockIdx.x, kvh = blockIdx.y, qs = blockIdx.z;  // heavy entries first
  int c, part, np;
  if (e < 7)       { c = e;               part = 0;           np = 1; }
  else if (e < 23) { c = 7 + ((e - 7) >> 1);  part = (e - 7) & 1;  np = 2; }
  else if (e < 47) { c = 15 + (e - 23) / 3;   part = (e - 23) % 3; np = 3; }
  else if (e < 79) { c = 23 + ((e - 47) >> 2); part = (e - 47) & 3; np = 4; }
  else             { c = 31;              part = e - 79;      np = 5; }
  const int nt = (c == 0) ? 1 : (c + 2);
  const int t0 = (part * nt) / np, t1 = ((part + 1) * nt) / np;

  const int tid = threadIdx.x, wave = tid >> 6, lane = tid & 63;
  const int h = kvh * 4 + wave;            // this wave's head
  const int bp = h * 84 + e;
  const int l31 = lane & 31, hf = lane >> 5;
  const int qrow = c * 64 + qs * 32 + l31;

  bf16x8 qf[8];
  {
    const u16* qp = Q + ((size_t)h * S_ + qrow) * D_ + hf * 8;
#pragma unroll
    for (int m = 0; m < 8; m++) qf[m] = *(const bf16x8*)(qp + m * 16);
  }
  float mq = -1e30f, lq = 0.f;
  f32x16 accO[4] = {};   // O^T: accO[dt][reg] = O[d = dt*32+(reg&3)+8*(reg>>2)+4*hf][q=l31]

  const int kgo = (tid >> 4) * 128 + (tid & 15) * 8;   // K: tile-local (row, col8)
  const int vgo = (tid >> 3) * 2048 + (tid & 7) * 8;   // V: (d row)*S + col8 ; S_==RLEN_
  u16* const kdst = Kl + wave * 512;                   // + p*2048

  const int cm1 = (c >= 1) ? (c - 1) : 0;
  const u16* krb = Krs + (size_t)kvh * RLEN_ * D_ + (size_t)cm1 * 64 * D_;
  const u16* vrb = Vtrs + (size_t)kvh * D_ * RLEN_ + cm1 * 64;
  const u16* kst = Ksw + (size_t)kvh * S_ * D_ + (size_t)t0 * 64 * D_;
  const u16* vst = Vts + (size_t)kvh * D_ * S_ + t0 * 64;
  int ts = t0;

#pragma unroll
  for (int p = 0; p < 4; p++) GLL(kst + p * 2048 + kgo, kdst + p * 2048);
#pragma unroll
  for (int p = 0; p < 4; p++) GLL(vst + p * 65536 + vgo, Vl + wave * 512 + p * 2048);
  ts = t0 + 1;
  if (ts == c + 1) { kst = krb; vst = vrb; } else { kst += 64 * D_; vst += 64; }
  drain_then_sync();

  for (int t = t0; t < t1; t++) {
    const int vb = (t - t0) & 1;
    const bool pf = (t + 1 < t1);
    f32x16 sacc[2] = {};
    {
      const char* Kbuf = (const char*)Kl;
#pragma unroll
      for (int kb = 0; kb < 2; kb++)
#pragma unroll
        for (int m = 0; m < 8; m++) {
          int by = ((kb * 32 + l31) << 8) + ((m * 32 + hf * 16) ^ ((l31 & 7) << 4));
          bf16x8 kf = *(const bf16x8*)(Kbuf + by);
          sacc[kb] = __builtin_amdgcn_mfma_f32_32x32x16_bf16(kf, qf[m], sacc[kb], 0, 0, 0);
        }
    }
    drain_then_sync();  // bar1: V(t) proven landed; Kl reads done -> overwritable
    if (pf) {
#pragma unroll
      for (int p = 0; p < 4; p++) GLL(kst + p * 2048 + kgo, kdst + p * 2048);
      u16* vd = Vl + (vb ^ 1) * 8192 + wave * 512;
#pragma unroll
      for (int p = 0; p < 4; p++) GLL(vst + p * 65536 + vgo, vd + p * 2048);
      ts++;
      if (ts == c + 1) { kst = krb; vst = vrb; } else { kst += 64 * D_; vst += 64; }
    }
    if (t == c) {  // diagonal tile causal mask: key kb*32+kloc > q qs*32+l31
#pragma unroll
      for (int kb = 0; kb < 2; kb++) {
        const int koffm = kb * 32 - qs * 32;
#pragma unroll
        for (int r = 0; r < 16; r++) {
          int kloc = (r & 3) + 8 * (r >> 2) + 4 * hf + koffm;
          if (kloc > l31) sacc[kb][r] = -1e30f;
        }
      }
    }
    float tmax = sacc[0][0];
#pragma unroll
    for (int r = 1; r < 16; r++) tmax = fmaxf(tmax, sacc[0][r]);
#pragma unroll
    for (int r = 0; r < 16; r++) tmax = fmaxf(tmax, sacc[1][r]);
    tmax = xhalf_max(tmax);
    if (!__all(tmax - mq <= 11.5f)) {  // defer-rescale (T13)
      float mn = fmaxf(mq, tmax);
      float f = exp2v(mq - mn);
      mq = mn; lq *= f;
#pragma unroll
      for (int dt = 0; dt < 4; dt++)
#pragma unroll
        for (int r = 0; r < 16; r++) accO[dt][r] *= f;
    }
    float ps = 0.f;
#pragma unroll
    for (int kb = 0; kb < 2; kb++)
#pragma unroll
      for (int r = 0; r < 16; r++) {
        float p = exp2v(sacc[kb][r] - mq);
        sacc[kb][r] = p; ps += p;
      }
    lq += xhalf_add(ps);
    unsigned W[2][8];
#pragma unroll
    for (int kb = 0; kb < 2; kb++)
#pragma unroll
      for (int g = 0; g < 4; g++) {
        W[kb][2 * g]     = cvtpk(sacc[kb][4 * g],     sacc[kb][4 * g + 1]);
        W[kb][2 * g + 1] = cvtpk(sacc[kb][4 * g + 2], sacc[kb][4 * g + 3]);
      }
    const char* Vbuf = (const char*)(Vl + vb * 8192);
    __builtin_amdgcn_s_setprio(1);
#pragma unroll
    for (int kb = 0; kb < 2; kb++)
#pragma unroll
      for (int st = 0; st < 2; st++) {
        unsigned x0 = W[kb][4 * st], y0 = W[kb][4 * st + 2];
        unsigned x1 = W[kb][4 * st + 1], y1 = W[kb][4 * st + 3];
        pl32swap(x0, y0);
        pl32swap(x1, y1);
        union { unsigned u[4]; bf16x8 v; } pfr;
        pfr.u[0] = x0; pfr.u[1] = x1; pfr.u[2] = y0; pfr.u[3] = y1;
#pragma unroll
        for (int dt = 0; dt < 4; dt++) {
          int vby = ((dt * 32 + l31) << 7) +
                    ((kb * 64 + st * 32 + hf * 16) ^ ((l31 & 7) << 4));
          bf16x8 vf = *(const bf16x8*)(Vbuf + vby);
          accO[dt] = __builtin_amdgcn_mfma_f32_32x32x16_bf16(vf, pfr.v, accO[dt], 0, 0, 0);
        }
      }
    __builtin_amdgcn_s_setprio(0);
    if (pf) drain4_then_sync();  // bar2: K(t+1) (oldest 4 of 8) landed; V(t+1) in flight
  }

  u16* op = Opart + (size_t)bp * 8192 + (size_t)(qs * 32 + l31) * 128;
#pragma unroll
  for (int dt = 0; dt < 4; dt++)
#pragma unroll
    for (int j = 0; j < 4; j++) {
      u16x4 o;
#pragma unroll
      for (int b = 0; b < 4; b++) o[b] = f2bf(accO[dt][4 * j + b]);
      *(u16x4*)(op + dt * 32 + j * 8 + hf * 4) = o;
    }
  if (hf == 0) {
    Ml[(size_t)bp * 128 + qs * 32 + l31]      = mq;
    Ml[(size_t)bp * 128 + 64 + qs * 32 + l31] = lq;
  }
}

// ---------------- split-K combine: merge <=5 partials per (head, chunk); log2 domain ----------------
__global__ __launch_bounds__(256) void k_combine(const u16* __restrict__ Opart,
                                                 const float* __restrict__ Ml,
                                                 u16* __restrict__ attn) {
  const int c = blockIdx.x, h = blockIdx.y;
  const int t = threadIdx.x;
  const int q = t >> 2, d0 = (t & 3) * 32;
  int base, np;
  if (c < 7)       { base = c;                 np = 1; }
  else if (c < 15) { base = 7 + 2 * (c - 7);   np = 2; }
  else if (c < 23) { base = 23 + 3 * (c - 15); np = 3; }
  else if (c < 31) { base = 47 + 4 * (c - 23); np = 4; }
  else             { base = 79;                np = 5; }
  const size_t pb = (size_t)h * 84 + base;

  float m = -1e30f;
  for (int p = 0; p < np; p++) m = fmaxf(m, Ml[(pb + p) * 128 + q]);
  float l = 0.f;
  float N[32];
#pragma unroll
  for (int i = 0; i < 32; i++) N[i] = 0.f;
  for (int p = 0; p < np; p++) {
    const float mp = Ml[(pb + p) * 128 + q];
    const float lp = Ml[(pb + p) * 128 + 64 + q];
    const float w = exp2v(mp - m);
    l += w * lp;
    const u16* op = Opart + (pb + p) * 8192 + q * 128 + d0;
#pragma unroll
    for (int i = 0; i < 4; i++) {
      u16x8 v = ((const u16x8*)op)[i];
#pragma unroll
      for (int ee = 0; ee < 8; ee++) N[i * 8 + ee] += w * bf2f(v[ee]);
    }
  }
  const float inv = 1.f / l;
  u16* dst = attn + (size_t)(c * 64 + q) * (H_ * D_) + h * 128 + d0;
#pragma unroll
  for (int i = 0; i < 4; i++) {
    u16x8 o;
#pragma unroll
    for (int ee = 0; ee < 8; ee++) o[ee] = f2bf(N[i * 8 + ee] * inv);
    ((u16x8*)dst)[i] = o;
  }
}

extern "C" void kernel_launch(void* const* d_in, const int* in_sizes, int n_in,
                              void* d_out, int out_size, void* d_ws, size_t ws_size,
                              hipStream_t stream) {
  const float* hs = (const float*)d_in[0];
  const float* cs = (const float*)d_in[1];
  const float* sn = (const float*)d_in[2];
  const float* rk = (const float*)d_in[3];
  const float* rv = (const float*)d_in[4];
  const float* Wq = (const float*)d_in[5];
  const float* Wk = (const float*)d_in[6];
  const float* Wv = (const float*)d_in[7];
  const float* Wo = (const float*)d_in[8];
  float* out = (float*)d_out;
  char* ws = (char*)d_ws;
  if (ws_size < (size_t)(56u << 20)) return;  // fail visibly (output stays poisoned)

  // ---- workspace choreography (identical regions to R17; hazard-walked) ----
  // phase-1 (prep1+gemm1): hsb@0..8 | wtq@8..20 | qkvP@20..44 (2x12MB bf16 partials)
  u16* hsb  = (u16*)(ws);                 // 8MB  @0
  u16* wtq  = (u16*)(ws + (8u << 20));    // 12MB @8
  u16* qkvP = (u16*)(ws + (20u << 20));   // 24MB @20
  // phase-2 (prep2): reads qkvP@20..44 + inputs; writes Qr@44, Ks@52, Vts@54,
  //                  Krs@8, Vtrs@10, wto@12 (hsb/wtq dead after gemm1; all disjoint)
  u16* Qr   = (u16*)(ws + (44u << 20));   // 8MB  @44
  u16* Ks   = (u16*)(ws + (52u << 20));   // 2MB  @52
  u16* Vts  = (u16*)(ws + (54u << 20));   // 2MB  @54
  u16* Krs  = (u16*)(ws + (8u << 20));    // 2MB  @8
  u16* Vtrs = (u16*)(ws + (10u << 20));   // 2MB  @10
  u16* wto  = (u16*)(ws + (12u << 20));   // 8MB  @12..20
  // k_attn: reads @44..56, @8..12; writes Opart@20..41, Ml@41..42 (qkvP dead)
  u16* Opart= (u16*)(ws + (20u << 20));   // 21MB @20..41
  float* Ml = (float*)(ws + (41u << 20)); // 0.7MB @41
  // phase-3: attn@0..8 (hsb dead); Cp@20..36 2x8MB bf16 (Opart dead after combine)
  u16* attn = (u16*)(ws);
  u16* Cp   = (u16*)(ws + (20u << 20));

  k_prep1<<<10240, 256, 0, stream>>>(hs, Wq, Wk, Wv, hsb, wtq);
  k_gemm<<<dim3(24, 16, 2), 256, 0, stream>>>(hsb, wtq, qkvP, 2048, 3072, 2048, 1024, 0);
  k_prep2<<<18432, 256, 0, stream>>>(qkvP, cs, sn, rk, rv, Wo, Qr, Ks, Vts, Krs, Vtrs, wto);
  k_attn<<<dim3(84, 4, 2), 256, 0, stream>>>(Qr, Ks, Vts, Krs, Vtrs, Opart, Ml);
  k_combine<<<dim3(32, 16), 256, 0, stream>>>(Opart, Ml, attn);
  k_gemm<<<dim3(16, 16, 2), 256, 0, stream>>>(attn, wto, Cp, 2048, 2048, 2048, 1024, 0);
  k_comb2<<<2048, 256, 0, stream>>>(Cp, Cp + (size_t)2048 * 2048, out, 524288);
}